// Round 7
// baseline (848.595 us; speedup 1.0000x reference)
//
#include <hip/hip_runtime.h>

// STTEncoder: multi-scale foveation via integral image, bit-exact vs the
// XLA ReduceWindowRewriter (base_length=16) f32 cumsum tree (verified R6,
// absmax 0.0):
//   scan(z[0..1280]) pad to 81 tiles of 16:
//     inner[t][j] sequential; ts[t]=inner[t][15]
//     level2: i2 = sequential prefix of ts within 16-tile blocks; ts2[u]
//     level3: o2 = sequential scan of ts2
//     out[t] = (t>>4 ? o2[(t>>4)-1] + i2[t] : i2[t])
//     scan_at(c) = (c>>4 ? out[(c>>4)-1] + ip[c] : ip[c])
// Key perf insight: this tree streams with O(1) per-thread state (inAcc,
// i2Acc, o2Acc, outPrev) -> thread-per-line kernels, NO LDS, NO barriers.
// Chunks of 16 floats = 4 aligned dwordx4 per thread = exactly one 64B line
// (MSHR-merged); 3-buffer rotating prefetch keeps ~8KB/wave in flight.
// Layouts: r[bc][xIdx][y] (pass1 stores wave-contiguous, pass2 reads
// contiguous columns); ii[bc][yIdx][xIdx].

#define PATTERN   1280
#define NPAD      1281
#define TOKSZ     16
#define NTOK      172
#define NB        16
#define NC        3

constexpr int kStrides[5] = {1, 2, 4, 6, 8};
constexpr int kGrids[5]   = {4, 4, 6, 8, 10};

// ---------------- token table ----------------
struct TokTable { short x[NTOK]; short y[NTOK]; short s[NTOK]; };

constexpr int count_tokens() {
    int n = 0, plo = -1, phi = -1;
    for (int k = 0; k < 5; k++) {
        const int s = kStrides[k], g = kGrids[k];
        const int cov = g * TOKSZ * s;
        const int off = (PATTERN - cov) / 2;
        for (int j = 0; j < g; j++)
            for (int i = 0; i < g; i++) {
                const int x = off + i * TOKSZ * s;
                const int y = off + j * TOKSZ * s;
                if (plo >= 0 && x >= plo && x + TOKSZ * s <= phi &&
                    y >= plo && y + TOKSZ * s <= phi)
                    continue;
                n++;
            }
        plo = off; phi = off + cov;
    }
    return n;
}
static_assert(count_tokens() == NTOK, "token count mismatch");

constexpr TokTable build_tokens() {
    TokTable r{};
    int n = 0, plo = -1, phi = -1;
    for (int k = 0; k < 5; k++) {
        const int s = kStrides[k], g = kGrids[k];
        const int cov = g * TOKSZ * s;
        const int off = (PATTERN - cov) / 2;
        for (int j = 0; j < g; j++)
            for (int i = 0; i < g; i++) {
                const int x = off + i * TOKSZ * s;
                const int y = off + j * TOKSZ * s;
                if (plo >= 0 && x >= plo && x + TOKSZ * s <= phi &&
                    y >= plo && y + TOKSZ * s <= phi)
                    continue;
                r.x[n] = (short)x; r.y[n] = (short)y; r.s[n] = (short)s; n++;
            }
        plo = off; phi = off + cov;
    }
    return r;
}
__constant__ TokTable c_toks = build_tokens();

// ---------------- needed-coordinate set ----------------
struct Marks { bool m[NPAD]; };
constexpr Marks build_marks() {
    Marks mk{};
    for (int k = 0; k < 5; k++) {
        const int s = kStrides[k], g = kGrids[k];
        const int cov = g * TOKSZ * s;
        const int off = (PATTERN - cov) / 2;
        for (int m = 0; m <= TOKSZ * g; m++) mk.m[off + s * m] = true;
    }
    return mk;
}

struct CoordSet { short idx[NPAD]; int n; };
constexpr CoordSet build_coords() {
    CoordSet cs{};
    const Marks mk = build_marks();
    int n = 0;
    for (int p = 0; p < NPAD; p++)
        cs.idx[p] = mk.m[p] ? (short)(n++) : (short)(-1);
    cs.n = n;
    return cs;
}
constexpr CoordSet kCoords = build_coords();
constexpr int NCOORD = kCoords.n;   // 342
static_assert(kCoords.idx[0] == 0, "coordinate 0 must be checkpoint 0");
__constant__ CoordSet c_coords = build_coords();

// per-chunk checkpoint table: chunk m covers padded p = 16m+1 .. 16m+16;
// at[m][k] = checkpoint index of p=16m+k+1, or -1.
struct CkTab { short at[80][16]; };
constexpr CkTab build_cktab() {
    CkTab t{};
    const Marks mk = build_marks();
    int run = 1;                      // checkpoint 0 = coordinate 0
    for (int m = 0; m < 80; m++)
        for (int k = 0; k < 16; k++) {
            const int p = 16 * m + k + 1;
            t.at[m][k] = mk.m[p] ? (short)(run++) : (short)(-1);
        }
    return t;
}
constexpr CkTab kCk = build_cktab();

// ---------------- streaming scan pass (both directions) ----------------
// One thread = one line of 1280 contiguous floats (in + line*1280).
// Replicates the XLA tree exactly with O(1) state. LPB = lines per bc =
// output stride; checkpoint ck of line li in image bc is written to
// outp[(bc*NCOORD + ck)*LPB + li].
template <int LPB>
__global__ void __launch_bounds__(64)
scan_pass(const float* __restrict__ in, float* __restrict__ outp, int nLines) {
    const int line = blockIdx.x * 64 + threadIdx.x;
    if (line >= nLines) return;
    const int bc = line / LPB;
    const int li = line - bc * LPB;
    const float4* s4 = (const float4*)(in + (size_t)line * PATTERN);
    float* obase = outp + ((size_t)bc * NCOORD) * LPB + li;

    obase[0] = 0.0f;                  // checkpoint 0 = coordinate 0 (border)

    float4 buf[3][4];
#pragma unroll
    for (int q = 0; q < 4; q++) buf[0][q] = s4[q];
#pragma unroll
    for (int q = 0; q < 4; q++) buf[1][q] = s4[4 + q];

    float inAcc = 0.0f, i2Acc = 0.0f, o2Acc = 0.0f, outPrev = 0.0f;

#pragma unroll
    for (int m = 0; m < 80; m++) {
        if (m + 2 < 80) {
#pragma unroll
            for (int q = 0; q < 4; q++) buf[(m + 2) % 3][q] = s4[(m + 2) * 4 + q];
        }
        const float* v = (const float*)buf[m % 3];
#pragma unroll
        for (int k = 0; k < 16; k++) {
            if (k == 15) {
                // finalize tile m (elements p=16m..16m+15 all consumed)
                const float i2New = i2Acc + inAcc;           // i2[m]
                outPrev = (m >= 16) ? (o2Acc + i2New) : i2New;  // out[m]
                if ((m & 15) == 15) { o2Acc = outPrev; i2Acc = 0.0f; }
                else                { i2Acc = i2New; }
                inAcc = 0.0f;                                 // start tile m+1
            }
            inAcc += v[k];                                    // z[16m+k+1]
            if (kCk.at[m][k] >= 0) {
                const bool t0 = (m == 0 && k < 15);
                const float val = t0 ? inAcc : (outPrev + inAcc);
                obase[(size_t)kCk.at[m][k] * LPB] = val;
            }
        }
    }
}

// ---------------- pass 3: gather ----------------
// box = ((ii[yu,xu] - ii[yu,xl]) - ii[yl,xu]) + ii[yl,xl]; out = box / s^2.
// ii stored as [bc][yIdx][xIdx].
__global__ void __launch_bounds__(256)
pass3_gather(const float* __restrict__ ii, float* __restrict__ out, int bStart) {
    const int blk = blockIdx.x;          // lb*NTOK*NC + t*NC + c
    const int c  = blk % NC;
    const int bt = blk / NC;
    const int t  = bt % NTOK;
    const int lb = bt / NTOK;
    const int b  = bStart + lb;

    const int x0 = c_toks.x[t];
    const int y0 = c_toks.y[t];
    const int s  = c_toks.s[t];
    const int tid = threadIdx.x;
    const int gx = tid & 15, gy = tid >> 4;

    const int xl = x0 + s * gx, xu = xl + s;
    const int yl = y0 + s * gy, yu = yl + s;
    const int xli = c_coords.idx[xl], xui = c_coords.idx[xu];
    const int yli = c_coords.idx[yl], yui = c_coords.idx[yu];

    const float* iis = ii + (size_t)(lb * NC + c) * NCOORD * NCOORD;
    const float A = iis[(size_t)yui * NCOORD + xui];   // ii[yu, xu]
    const float B = iis[(size_t)yui * NCOORD + xli];   // ii[yu, xl]
    const float C = iis[(size_t)yli * NCOORD + xui];   // ii[yl, xu]
    const float D = iis[(size_t)yli * NCOORD + xli];   // ii[yl, xl]
    const float box = ((A - B) - C) + D;
    out[((size_t)(b * NTOK + t) * NC + c) * (TOKSZ * TOKSZ) + tid] =
        box / (float)(s * s);
}

extern "C" void kernel_launch(void* const* d_in, const int* in_sizes, int n_in,
                              void* d_out, int out_size, void* d_ws, size_t ws_size,
                              hipStream_t stream) {
    const float* in  = (const float*)d_in[0];
    float*       out = (float*)d_out;

    const size_t rPerBC  = (size_t)NCOORD * PATTERN * sizeof(float);   // ~1.75 MB
    const size_t iiPerBC = (size_t)NCOORD * NCOORD * sizeof(float);    // ~0.47 MB
    const size_t perB    = (size_t)NC * (rPerBC + iiPerBC);            // ~6.66 MB

    int chunkB = (int)(ws_size / perB);
    if (chunkB < 1)  chunkB = 1;     // undersized ws: best effort
    if (chunkB > NB) chunkB = NB;

    float* rbuf  = (float*)d_ws;
    float* iibuf = (float*)((char*)d_ws + (size_t)chunkB * NC * rPerBC);

    for (int b0 = 0; b0 < NB; b0 += chunkB) {
        const int nb = (b0 + chunkB <= NB) ? chunkB : (NB - b0);
        const int bcCount = nb * NC;

        // pass1: x-scans. lines = image rows (contiguous), flat over bc.
        // writes r[bc][xIdx][y]
        const int n1 = bcCount * PATTERN;
        scan_pass<PATTERN><<<dim3((n1 + 63) / 64), dim3(64), 0, stream>>>(
            in + (size_t)(b0 * NC) * PATTERN * PATTERN, rbuf, n1);

        // pass2: y-scans. lines = r columns (contiguous), 342 per bc.
        // writes ii[bc][yIdx][xIdx]
        const int n2 = bcCount * NCOORD;
        scan_pass<NCOORD><<<dim3((n2 + 63) / 64), dim3(64), 0, stream>>>(
            rbuf, iibuf, n2);

        pass3_gather<<<dim3(nb * NTOK * NC), dim3(256), 0, stream>>>(
            iibuf, out, b0);
    }
}